// Round 14
// baseline (303.357 us; speedup 1.0000x reference)
//
#include <hip/hip_runtime.h>
#include <hip/hip_bf16.h>
#include <stdint.h>

// ---------------------------------------------------------------------------
// Performer attention, round 13: contract_mfma -> 8 waves, row-groups (rg)
// parallel across wave quads (16 waves/CU, barriers 10->6/block).
// qkv: r12 8-wave BK64-dbuf 128² (115 µs). Everything else = r12.
// ---------------------------------------------------------------------------

#define DN 0.35355339059327379f   // 64^-0.25
#define EPSF 1e-6f
#define INV_SQRT_M 0.0625f        // 1/sqrt(256)

typedef __attribute__((ext_vector_type(8))) short bf16x8;
typedef __attribute__((ext_vector_type(4))) float f32x4;

static __device__ __forceinline__ short f2bf(float f) {
    __hip_bfloat16 h = __float2bfloat16(f);
    return *(short*)&h;
}
static __device__ __forceinline__ void gload16(const void* g, void* l) {
    __builtin_amdgcn_global_load_lds(
        (const __attribute__((address_space(1))) void*)g,
        (__attribute__((address_space(3))) void*)l,
        16, 0, 0);
}

// ---------------- K0: merged prep (x->bf16, w transposes, proj swizzle) ----
__global__ __launch_bounds__(256) void prep(const float* __restrict__ X,
                                            short* __restrict__ Xb,
                                            const float* __restrict__ Wq,
                                            short* __restrict__ WqT,
                                            const float* __restrict__ Wo,
                                            short* __restrict__ WoT,
                                            const float* __restrict__ proj,
                                            short* __restrict__ pjb) {
    __shared__ short tile[64][66];
    int b = blockIdx.x, t = threadIdx.x;
    if (b < 16384) {                           // conv_x
        int i = b * 256 + t;
        float4 v = ((const float4*)X)[i];
        short4 o;
        o.x = f2bf(v.x); o.y = f2bf(v.y); o.z = f2bf(v.z); o.w = f2bf(v.w);
        ((short4*)Xb)[i] = o;
    } else if (b < 17152) {                    // convt wq (48x16)
        int idx = b - 16384;
        int k0 = (idx / 48) * 64, n0 = (idx % 48) * 64;
        const int K = 1024, NN = 3072;
        for (int i = t; i < 4096; i += 256) {
            int r = i >> 6, c = i & 63;
            tile[r][c] = f2bf(Wq[(size_t)(k0 + r) * NN + n0 + c]);
        }
        __syncthreads();
        for (int i = t; i < 4096; i += 256) {
            int r = i >> 6, c = i & 63;
            WqT[(size_t)(n0 + r) * K + k0 + c] = tile[c][r];
        }
    } else if (b < 17408) {                    // convt wo (16x16)
        int idx = b - 17152;
        int k0 = (idx / 16) * 64, n0 = (idx % 16) * 64;
        const int K = 1024, NN = 1024;
        for (int i = t; i < 4096; i += 256) {
            int r = i >> 6, c = i & 63;
            tile[r][c] = f2bf(Wo[(size_t)(k0 + r) * NN + n0 + c]);
        }
        __syncthreads();
        for (int i = t; i < 4096; i += 256) {
            int r = i >> 6, c = i & 63;
            WoT[(size_t)(n0 + r) * K + k0 + c] = tile[c][r];
        }
    } else {                                   // conv_proj
        int e = (b - 17408) * 256 + t;
        int m = (e >> 6) & 255, d = e & 63;
        int base = e & ~63;
        pjb[base + (d ^ ((m & 7) << 3))] = f2bf(proj[e]);
    }
}

// ---------------- K1: 8-wave MFMA GEMM -> Q,K (swz,*DN), V^T ---------------
__global__ __launch_bounds__(512, 4) void mfma_gemm_qkv(
        const short* __restrict__ A, const short* __restrict__ BT,
        const float* __restrict__ bias,
        short* __restrict__ Qh, short* __restrict__ Kh, short* __restrict__ Vt) {
    __shared__ __align__(16) char smem[65536];
    const int K = 1024;
    int t = threadIdx.x, lane = t & 63, w = t >> 6;
    int li = lane & 15, g = lane >> 4;
    int wm = w >> 2, wn = w & 3;
    int lin = blockIdx.x;                        // 3072 = 24 x 128, plain
    int bx = lin % 24, by = lin / 24;
    int rowBase = by * 128, colBase = bx * 128;

    const char* aSrc[2]; const char* bSrc[2]; int aOff[2];
#pragma unroll
    for (int c = 0; c < 2; ++c) {
        int idx = c * 512 + t;
        int r = idx >> 3, s = t & 7;
        aOff[c] = idx * 16;
        aSrc[c] = (const char*)(A + (size_t)(rowBase + r) * K + ((s ^ (r & 7)) * 8));
        bSrc[c] = (const char*)(BT + (size_t)(colBase + r) * K + ((s ^ (r & 7)) * 8));
    }

    f32x4 acc[4][2];
#pragma unroll
    for (int m = 0; m < 4; ++m)
#pragma unroll
        for (int n = 0; n < 2; ++n) acc[m][n] = (f32x4){0.f, 0.f, 0.f, 0.f};

#pragma unroll
    for (int c = 0; c < 2; ++c) {
        gload16(aSrc[c], smem + aOff[c]);
        gload16(bSrc[c], smem + 16384 + aOff[c]);
    }

    int swz = (li & 7) << 4;

    for (int tt = 0; tt < 16; ++tt) {
        int cur = tt & 1;
        if (tt < 15) {
            char* d = smem + (cur ^ 1) * 32768;
#pragma unroll
            for (int c = 0; c < 2; ++c) {
                gload16(aSrc[c] + (size_t)(tt + 1) * 128, d + aOff[c]);
                gload16(bSrc[c] + (size_t)(tt + 1) * 128, d + 16384 + aOff[c]);
            }
            asm volatile("s_waitcnt vmcnt(4)" ::: "memory");
        } else {
            asm volatile("s_waitcnt vmcnt(0)" ::: "memory");
        }
        __builtin_amdgcn_sched_barrier(0);
        __builtin_amdgcn_s_barrier();
        __builtin_amdgcn_sched_barrier(0);
        __builtin_amdgcn_s_setprio(1);
        const char* bA = smem + cur * 32768;
        const char* bB = bA + 16384;
#pragma unroll
        for (int ks = 0; ks < 2; ++ks) {
            int kb = ks * 64 + g * 16;
            bf16x8 af[4], bv[2];
#pragma unroll
            for (int m = 0; m < 4; ++m)
                af[m] = *(const bf16x8*)(bA + (wm * 64 + m * 16 + li) * 128 + (kb ^ swz));
#pragma unroll
            for (int n = 0; n < 2; ++n)
                bv[n] = *(const bf16x8*)(bB + (wn * 32 + n * 16 + li) * 128 + (kb ^ swz));
#pragma unroll
            for (int m = 0; m < 4; ++m)
#pragma unroll
                for (int n = 0; n < 2; ++n)
                    acc[m][n] = __builtin_amdgcn_mfma_f32_16x16x32_bf16(
                        af[m], bv[n], acc[m][n], 0, 0, 0);
        }
        __builtin_amdgcn_s_setprio(0);
        __builtin_amdgcn_sched_barrier(0);
        __builtin_amdgcn_s_barrier();
        __builtin_amdgcn_sched_barrier(0);
    }

    float bcol[2];
#pragma unroll
    for (int n = 0; n < 2; ++n) bcol[n] = bias[colBase + wn * 32 + n * 16 + li];
    int whichB = colBase >> 10;

    if (whichB == 2) {
#pragma unroll
        for (int n = 0; n < 2; ++n) {
            int gc = colBase + wn * 32 + n * 16 + li;
            int hh = (gc & 1023) >> 6, dd = gc & 63;
#pragma unroll
            for (int m = 0; m < 4; ++m) {
                int gr0 = rowBase + wm * 64 + m * 16 + g * 4;
                int b = gr0 >> 12, nn0 = gr0 & 4095;
                short4 o;
                o.x = f2bf(acc[m][n][0] + bcol[n]);
                o.y = f2bf(acc[m][n][1] + bcol[n]);
                o.z = f2bf(acc[m][n][2] + bcol[n]);
                o.w = f2bf(acc[m][n][3] + bcol[n]);
                int nsw = (nn0 & ~63) | ((nn0 & 63) ^ ((dd & 7) << 3));
                *(short4*)&Vt[((size_t)(b * 16 + hh) * 64 + dd) * 4096 + nsw] = o;
            }
        }
    } else {
        short* dst = (whichB == 0) ? Qh : Kh;
        int hh = ((colBase + wn * 32) & 1023) >> 6;
        float* wreg = (float*)(smem + w * 4608);   // [32][36] f32
#pragma unroll
        for (int r = 0; r < 2; ++r) {
#pragma unroll
            for (int fr2 = 0; fr2 < 2; ++fr2)
#pragma unroll
                for (int n = 0; n < 2; ++n)
#pragma unroll
                    for (int jj = 0; jj < 4; ++jj)
                        wreg[(fr2 * 16 + g * 4 + jj) * 36 + n * 16 + li] =
                            (acc[2 * r + fr2][n][jj] + bcol[n]) * DN;
            int row2 = lane >> 1, h2 = lane & 1;
            int tok = rowBase + wm * 64 + r * 32 + row2;
            int b = tok >> 12, nn = tok & 4095;
            size_t base = ((size_t)(b * 16 + hh) * 4096 + nn) * 64;
#pragma unroll
            for (int k = 0; k < 2; ++k) {
                float4 v0 = *(const float4*)&wreg[row2 * 36 + h2 * 16 + k * 8];
                float4 v1 = *(const float4*)&wreg[row2 * 36 + h2 * 16 + k * 8 + 4];
                bf16x8 ov;
                ov[0] = f2bf(v0.x); ov[1] = f2bf(v0.y);
                ov[2] = f2bf(v0.z); ov[3] = f2bf(v0.w);
                ov[4] = f2bf(v1.x); ov[5] = f2bf(v1.y);
                ov[6] = f2bf(v1.z); ov[7] = f2bf(v1.w);
                int dgrp = ((wn & 1) * 4 + h2 * 2 + k) ^ (tok & 7);
                *(bf16x8*)&dst[base + dgrp * 8] = ov;
            }
            __builtin_amdgcn_s_barrier();
        }
    }
}

// ------- r8 256x256 8-phase GEMM core (used by gemm_out only) --------------
template<int Q, int S>
static __device__ __forceinline__ void phase_compute(
        const char* smem, int tt, int wm, int wn, int li, int g, int swz,
        f32x4 (&acc)[2][4][2][2]) {
    const char* bA = smem + ((tt & 1) << 16) + (Q << 14);
    const char* bB = smem + ((tt & 1) << 16) + 32768 + (S << 14);
    bf16x8 af[4][2], bf[2][2];
#pragma unroll
    for (int fr = 0; fr < 4; ++fr) {
        int row = wm * 64 + fr * 16 + li;
#pragma unroll
        for (int kk = 0; kk < 2; ++kk)
            af[fr][kk] = *(const bf16x8*)(bA + row * 128 + ((kk * 64 + g * 16) ^ swz));
    }
#pragma unroll
    for (int fn = 0; fn < 2; ++fn) {
        int row = wn * 32 + fn * 16 + li;
#pragma unroll
        for (int kk = 0; kk < 2; ++kk)
            bf[fn][kk] = *(const bf16x8*)(bB + row * 128 + ((kk * 64 + g * 16) ^ swz));
    }
    __builtin_amdgcn_s_setprio(1);
#pragma unroll
    for (int kk = 0; kk < 2; ++kk)
#pragma unroll
        for (int fr = 0; fr < 4; ++fr)
#pragma unroll
            for (int fn = 0; fn < 2; ++fn)
                acc[Q][fr][S][fn] = __builtin_amdgcn_mfma_f32_16x16x32_bf16(
                    af[fr][kk], bf[fn][kk], acc[Q][fr][S][fn], 0, 0, 0);
    __builtin_amdgcn_s_setprio(0);
}

static __device__ __forceinline__ void gemm_core256(const short* __restrict__ A,
                                                    const short* __restrict__ BT,
                                                    int rowBase, int colBase,
                                                    char* smem,
                                                    f32x4 (&acc)[2][4][2][2]) {
    const int K = 1024;
    int t = threadIdx.x, lane = t & 63;
    int li = lane & 15, g = lane >> 4;
    int w = t >> 6, wm = w >> 2, wn = w & 3;
    int swz = (li & 7) << 4;

    int idxA = t, idxB = 512 + t;
    int rA = idxA >> 3, sA = idxA & 7;
    int rB = idxB >> 3, sB = idxB & 7;
    const char* Ab = (const char*)(A + (size_t)rowBase * K);
    const char* Bb = (const char*)(BT + (size_t)colBase * K);
    int srcOffA = rA * 2048 + ((sA ^ (rA & 7)) * 16);
    int srcOffB = rB * 2048 + ((sB ^ (rB & 7)) * 16);
    int dstOffA = idxA * 16, dstOffB = idxB * 16;

#define STG(op_, half_, tile_) do {                                           \
    char* d_ = smem + (((tile_) & 1) << 16) + ((op_) << 15) + ((half_) << 14);\
    const char* s_ = ((op_) ? Bb : Ab) + (half_) * 262144 + (tile_) * 128;    \
    gload16(s_ + srcOffA, d_ + dstOffA);                                      \
    gload16(s_ + srcOffB, d_ + dstOffB);                                      \
} while (0)

#define PH(q_, s_, vm_, dost_, sop_, shalf_, stile_) do {                     \
    if (dost_) STG(sop_, shalf_, stile_);                                     \
    asm volatile("s_waitcnt vmcnt(" #vm_ ")" ::: "memory");                   \
    __builtin_amdgcn_sched_barrier(0);                                        \
    __builtin_amdgcn_s_barrier();                                             \
    __builtin_amdgcn_sched_barrier(0);                                        \
    phase_compute<q_, s_>(smem, tt, wm, wn, li, g, swz, acc);                 \
} while (0)

#pragma unroll
    for (int q = 0; q < 2; ++q)
#pragma unroll
        for (int fr = 0; fr < 4; ++fr)
#pragma unroll
            for (int s = 0; s < 2; ++s)
#pragma unroll
                for (int fn = 0; fn < 2; ++fn)
                    acc[q][fr][s][fn] = (f32x4){0.f, 0.f, 0.f, 0.f};

    STG(1, 0, 0);
    STG(0, 1, 0);
    STG(0, 0, 0);
    STG(1, 1, 0);
    STG(1, 0, 1);
    STG(0, 1, 1);

    for (int tt = 0; tt < 14; ++tt) {
        PH(0, 0,  8, true, 0, 0, tt + 1);
        PH(1, 0, 12, true, 1, 1, tt + 1);
        PH(1, 1, 10, true, 1, 0, tt + 2);
        PH(0, 1, 12, true, 0, 1, tt + 2);
    }
    {
        int tt = 14;
        PH(0, 0,  8, true, 0, 0, 15);
        PH(1, 0, 12, true, 1, 1, 15);
        PH(1, 1,  8, false, 0, 0, 0);
        PH(0, 1,  8, false, 0, 0, 0);
    }
    {
        int tt = 15;
        PH(0, 0, 2, false, 0, 0, 0);
        PH(1, 0, 4, false, 0, 0, 0);
        PH(1, 1, 0, false, 0, 0, 0);
        PH(0, 1, 0, false, 0, 0, 0);
    }
    __builtin_amdgcn_s_barrier();
#undef PH
#undef STG
}

// ---------------- K5: 8-phase MFMA GEMM -> d_out f32 -----------------------
__global__ __launch_bounds__(512) void mfma_gemm_out(
        const short* __restrict__ A, const short* __restrict__ BT,
        const float* __restrict__ bias, float* __restrict__ C) {
    __shared__ __align__(16) char smem[131072];
    int lin = blockIdx.x;                        // 256 = 4 x 64
    int bx = lin & 3, by = lin >> 2;
    int rowBase = by * 256, colBase = bx * 256;

    f32x4 acc[2][4][2][2];
    gemm_core256(A, BT, rowBase, colBase, smem, acc);

    int t = threadIdx.x, lane = t & 63, w = t >> 6;
    int li = lane & 15, g = lane >> 4, wm = w >> 2, wn = w & 3;
    float bcol[2][2];
#pragma unroll
    for (int s = 0; s < 2; ++s)
#pragma unroll
        for (int fn = 0; fn < 2; ++fn)
            bcol[s][fn] = bias[colBase + s * 128 + wn * 32 + fn * 16 + li];

    float* wreg = (float*)(smem + w * 5632);     // [32][44] f32 per wave (pad)
#pragma unroll
    for (int q = 0; q < 2; ++q)
#pragma unroll
        for (int fp = 0; fp < 2; ++fp)
#pragma unroll
            for (int s = 0; s < 2; ++s) {
#pragma unroll
                for (int fr2 = 0; fr2 < 2; ++fr2)
#pragma unroll
                    for (int fn = 0; fn < 2; ++fn)
#pragma unroll
                        for (int jj = 0; jj < 4; ++jj)
                            wreg[(fr2 * 16 + g * 4 + jj) * 44 + fn * 16 + li] =
                                acc[q][fp * 2 + fr2][s][fn][jj] + bcol[s][fn];
                int row2 = lane >> 1, hh2 = lane & 1;
                int gr = rowBase + q * 128 + wm * 64 + fp * 32 + row2;
                float* cp = C + (size_t)gr * 1024 + colBase + s * 128 + wn * 32 + hh2 * 16;
#pragma unroll
                for (int k = 0; k < 4; ++k)
                    *(float4*)&cp[k * 4] = *(const float4*)&wreg[row2 * 44 + hh2 * 16 + k * 4];
            }
}

// ------- K2: MFMA K feature map + kv/ksum partials (proj in regs) ----------
__global__ __launch_bounds__(256) void fmap_mfma(const short* __restrict__ Kh,
                                                 const short* __restrict__ Vt,
                                                 const short* __restrict__ pjb,
                                                 float* __restrict__ kvpart,
                                                 float* __restrict__ kspart) {
    int bh = blockIdx.y, ch = blockIdx.x, h = bh & 15;
    int t = threadIdx.x, lane = t & 63, w = t >> 6;
    int g = lane >> 4, li = lane & 15;
    __shared__ __align__(16) short kt[64 * 64];     //  8KB [n][d] swz
    __shared__ __align__(16) short vt[64 * 64];     //  8KB [d][n] swz
    __shared__ __align__(16) short Pl[4][64 * 40];  // 20KB per-wave, 80B rows
    __shared__ __align__(16) float maxw[4][64];     //  1KB

    const short* kbase = Kh + ((size_t)bh * 4096 + ch * 512) * 64;
    const short* vbase = Vt + (size_t)bh * 64 * 4096 + ch * 512;
    int swz = (li & 7) << 4;

    bf16x8 pjf[2][4];
    {
        const char* ph = (const char*)(pjb + (size_t)h * 16384);
#pragma unroll
        for (int ks = 0; ks < 2; ++ks)
#pragma unroll
            for (int mi = 0; mi < 4; ++mi)
                pjf[ks][mi] = *(const bf16x8*)(ph +
                    (64 * w + 16 * mi + li) * 128 + ((ks * 64 + g * 16) ^ swz));
    }

    {
#pragma unroll
        for (int c2 = 0; c2 < 2; ++c2) {
            int c = 2 * w + c2;
            gload16(kbase + c * 512 + lane * 8, kt + c * 512);
            int d = 8 * c + (lane >> 3);
            gload16(vbase + (size_t)d * 4096 + (lane & 7) * 8, vt + c * 512);
        }
    }
    __syncthreads();

    f32x4 acc[4][4];
#pragma unroll
    for (int i = 0; i < 4; ++i)
#pragma unroll
        for (int j = 0; j < 4; ++j) acc[i][j] = (f32x4){0.f, 0.f, 0.f, 0.f};
    float ksacc[4] = {0.f, 0.f, 0.f, 0.f};

    for (int tile = 0; tile < 8; ++tile) {
        bf16x8 rk0, rk1, rv0, rv1;
        if (tile < 7) {
            int c0 = 2 * w, c1 = 2 * w + 1;
            size_t kof = (size_t)((tile + 1) * 64) * 64;
            rk0 = *(const bf16x8*)(kbase + kof + c0 * 512 + lane * 8);
            rk1 = *(const bf16x8*)(kbase + kof + c1 * 512 + lane * 8);
            int d0 = 8 * c0 + (lane >> 3), d1 = 8 * c1 + (lane >> 3);
            rv0 = *(const bf16x8*)(vbase + (size_t)d0 * 4096 + (tile + 1) * 64 + (lane & 7) * 8);
            rv1 = *(const bf16x8*)(vbase + (size_t)d1 * 4096 + (tile + 1) * 64 + (lane & 7) * 8);
        }

        f32x4 sacc[4][4];
#pragma unroll
        for (int i = 0; i < 4; ++i)
#pragma unroll
            for (int j = 0; j < 4; ++j) sacc[i][j] = (f32x4){0.f, 0.f, 0.f, 0.f};
#pragma unroll
        for (int ks = 0; ks < 2; ++ks) {
            int kb = ks * 64 + g * 16;
            bf16x8 afr[4];
#pragma unroll
            for (int ni = 0; ni < 4; ++ni)
                afr[ni] = *(const bf16x8*)((const char*)kt +
                           (16 * ni + li) * 128 + (kb ^ swz));
#pragma unroll
            for (int ni = 0; ni < 4; ++ni)
#pragma unroll
                for (int mi = 0; mi < 4; ++mi)
                    sacc[ni][mi] = __builtin_amdgcn_mfma_f32_16x16x32_bf16(
                        afr[ni], pjf[ks][mi], sacc[ni][mi], 0, 0, 0);
        }

        float mxl[4][4];
#pragma unroll
        for (int ni = 0; ni < 4; ++ni)
#pragma unroll
            for (int jj = 0; jj < 4; ++jj) {
                float m0 = fmaxf(sacc[ni][0][jj], sacc[ni][1][jj]);
                float m1 = fmaxf(sacc[ni][2][jj], sacc[ni][3][jj]);
                mxl[ni][jj] = fmaxf(m0, m1);
            }
#pragma unroll
        for (int off = 1; off <= 8; off <<= 1)
#pragma unroll
            for (int ni = 0; ni < 4; ++ni)
#pragma unroll
                for (int jj = 0; jj < 4; ++jj)
                    mxl[ni][jj] = fmaxf(mxl[ni][jj], __shfl_xor(mxl[ni][jj], off));
        if (li == 0) {
#pragma unroll
            for (int ni = 0; ni < 4; ++ni)
                *(float4*)&maxw[w][16 * ni + 4 * g] =
                    make_float4(mxl[ni][0], mxl[ni][1], mxl[ni][2], mxl[ni][3]);
        }
        __syncthreads();

#pragma unroll
        for (int hf = 0; hf < 2; ++hf) {
#pragma unroll
            for (int ni2 = 0; ni2 < 2; ++ni2) {
                int ni = 2 * hf + ni2;
                float4 a0 = *(const float4*)&maxw[0][16 * ni + 4 * g];
                float4 a1 = *(const float4*)&maxw[1][16 * ni + 4 * g];
                float4 a2 = *(const float4*)&maxw[2][16 * ni + 4 * g];
                float4 a3 = *(const float4*)&maxw[3][16 * ni + 4 * g];
                float mm[4];
                mm[0] = fmaxf(fmaxf(a0.x, a1.x), fmaxf(a2.x, a3.x));
                mm[1] = fmaxf(fmaxf(a0.y, a1.y), fmaxf(a2.y, a3.y));
                mm[2] = fmaxf(fmaxf(a0.z, a1.z), fmaxf(a2.z, a3.z));
                mm[3] = fmaxf(fmaxf(a0.w, a1.w), fmaxf(a2.w, a3.w));
#pragma unroll
                for (int mi = 0; mi < 4; ++mi) {
                    float p0 = (__expf(sacc[ni][mi][0] - mm[0]) + EPSF) * INV_SQRT_M;
                    float p1 = (__expf(sacc[ni][mi][1] - mm[1]) + EPSF) * INV_SQRT_M;
                    float p2 = (__expf(sacc[ni][mi][2] - mm[2]) + EPSF) * INV_SQRT_M;
                    float p3 = (__expf(sacc[ni][mi][3] - mm[3]) + EPSF) * INV_SQRT_M;
                    ksacc[mi] += (p0 + p1) + (p2 + p3);
                    uint32_t u0 = (uint32_t)(uint16_t)f2bf(p0) |
                                  ((uint32_t)(uint16_t)f2bf(p1) << 16);
                    uint32_t u1 = (uint32_t)(uint16_t)f2bf(p2) |
                                  ((uint32_t)(uint16_t)f2bf(p3) << 16);
                    int m_l = 16 * mi + li;
                    *(uint2*)((char*)Pl[w] + m_l * 80 + 32 * ni2 + 8 * g) =
                        make_uint2(u0, u1);
                }
            }
#pragma unroll
            for (int mi = 0; mi < 4; ++mi) {
                bf16x8 pa = *(const bf16x8*)((const char*)Pl[w] +
                             (16 * mi + li) * 80 + 16 * g);
#pragma unroll
                for (int di = 0; di < 4; ++di) {
                    bf16x8 bv = *(const bf16x8*)((const char*)vt +
                                 (16 * di + li) * 128 + ((64 * hf + 16 * g) ^ swz));
                    acc[mi][di] = __builtin_amdgcn_mfma_f32_16x16x32_bf16(
                        pa, bv, acc[mi][di], 0, 0, 0);
                }
            }
        }
        __syncthreads();
        if (tile < 7) {
            int c0 = 2 * w, c1 = 2 * w + 1;
            *(bf16x8*)((char*)kt + c0 * 1024 + lane * 16) = rk0;
            *(bf16x8*)((char*)kt + c1 * 1024 + lane * 16) = rk1;
            *(bf16x8*)((char*)vt + c0 * 1024 + lane * 16) = rv0;
            *(bf16x8*)((char*)vt + c1 * 1024 + lane * 16) = rv1;
            __syncthreads();
        }
    }

#pragma unroll
    for (int mi = 0; mi < 4; ++mi) {
        ksacc[mi] += __shfl_xor(ksacc[mi], 16);
        ksacc[mi] += __shfl_xor(ksacc[mi], 32);
    }
    if (lane < 16) {
#pragma unroll
        for (int mi = 0; mi < 4; ++mi)
            kspart[(bh * 8 + ch) * 256 + 64 * w + 16 * mi + li] = ksacc[mi];
    }
    float* kvb = kvpart + (size_t)(bh * 8 + ch) * 16384;
#pragma unroll
    for (int mi = 0; mi < 4; ++mi)
#pragma unroll
        for (int di = 0; di < 4; ++di) {
            int d = 16 * di + li, m0 = 64 * w + 16 * mi + 4 * g;
            *(float4*)&kvb[d * 256 + m0] =
                make_float4(acc[mi][di][0], acc[mi][di][1],
                            acc[mi][di][2], acc[mi][di][3]);
        }
}

// ------- K3: reduce partials -> kvT_sw bf16 [bh][80][256] ------------------
__global__ __launch_bounds__(256) void reduce_kv(const float* __restrict__ kvpart,
                                                 const float* __restrict__ kspart,
                                                 short* __restrict__ kvsT) {
    int bh = blockIdx.y, bx = blockIdx.x, t = threadIdx.x;
    if (bx < 4) {
#pragma unroll
        for (int i = 0; i < 16; ++i) {
            int idx = t + i * 256;
            int d = 16 * bx + (idx >> 8), m = idx & 255;
            float s = 0.f;
            size_t base = ((size_t)(bh * 8) * 64 + d) * 256 + m;
#pragma unroll
            for (int c = 0; c < 8; ++c) s += kvpart[base + (size_t)c * 16384];
            int widx = (m & 128) + ((m & 127) ^ ((d & 7) << 3));
            kvsT[((size_t)bh * 80 + d) * 256 + widx] = f2bf(s);
        }
    } else {
        float s = 0.f;
#pragma unroll
        for (int c = 0; c < 8; ++c) s += kspart[((bh * 8 + c) << 8) + t];
        kvsT[((size_t)bh * 80 + 64) * 256 + t] = f2bf(s);
        for (int i = t; i < 15 * 256; i += 256) {
            int r = 65 + (i >> 8), cc = i & 255;
            kvsT[((size_t)bh * 80 + r) * 256 + cc] = 0;
        }
    }
}

// ------- K4: MFMA contract, QBLK=128, 8 waves (rg parallel across quads) ---
__global__ __launch_bounds__(512) void contract_mfma(
        const short* __restrict__ Qh,      // pre-swizzled, *DN
        const short* __restrict__ pjb,     // pre-swizzled bf16
        const short* __restrict__ kvsT,    // pre-swizzled bf16 [bh][80][256]
        short* __restrict__ attn) {
    int bh = blockIdx.y, rb = blockIdx.x, h = bh & 15, b = bh >> 4;
    int t = threadIdx.x, lane = t & 63, w = t >> 6;
    int rg = w >> 2, wq = w & 3;                   // row-group, quad-wave id
    __shared__ __align__(16) short qs[128 * 64];   // 16KB [row][d]      (swz)
    __shared__ __align__(16) short Pl[2][64 * 128];// 32KB [rg][row][m]  (swz)
    __shared__ __align__(16) short kvl[80 * 128];  // 20KB [d'][m]       (swz)

    // stage qs once: 16 chunks of 1KB; 2 per wave
    {
        const short* src = Qh + ((size_t)bh * 4096 + rb * 128) * 64;
#pragma unroll
        for (int c2 = 0; c2 < 2; ++c2) {
            int c = 2 * w + c2;
            gload16(src + (c * 8 + (lane >> 3)) * 64 + (lane & 7) * 8,
                    qs + c * 512);
        }
    }

    f32x4 acc5[5];
#pragma unroll
    for (int i = 0; i < 5; ++i) acc5[i] = (f32x4){0.f, 0.f, 0.f, 0.f};

    int g = lane >> 4, li = lane & 15;

    for (int half = 0; half < 2; ++half) {
        // proj frags to regs (per quad-wave m-slice)
        bf16x8 pjf[2][2];
        {
            const char* ph = (const char*)(pjb + (size_t)h * 16384 + half * 8192);
#pragma unroll
            for (int ks = 0; ks < 2; ++ks)
#pragma unroll
                for (int mi = 0; mi < 2; ++mi) {
                    int mr = 32 * wq + 16 * mi + li;
                    pjf[ks][mi] = *(const bf16x8*)(ph +
                        mr * 128 + ((ks * 64 + g * 16) ^ ((mr & 7) << 4)));
                }
        }
        // stage kvl: 20 chunks of 1KB across 8 waves (3,3,3,3,2,2,2,2)
        {
            const short* ksrc = kvsT + (size_t)bh * 80 * 256 + half * 128;
            int cbase = (w < 4) ? w * 3 : 12 + (w - 4) * 2;
            int cnum = (w < 4) ? 3 : 2;
            for (int c2 = 0; c2 < cnum; ++c2) {
                int c = cbase + c2;
                gload16(ksrc + (c * 4 + (lane >> 4)) * 256 + (lane & 15) * 8,
                        kvl + c * 512);
            }
        }
        __syncthreads();               // staged (drains DMA); prev C reads done

        // phase A: S^T tile [m: 32wq..+31][rows of rg]
        f32x4 sacc[2][4];
#pragma unroll
        for (int mi = 0; mi < 2; ++mi)
#pragma unroll
            for (int ni = 0; ni < 4; ++ni) sacc[mi][ni] = (f32x4){0.f, 0.f, 0.f, 0.f};
#pragma unroll
        for (int ks = 0; ks < 2; ++ks) {
            int kbyte = ks * 64 + g * 16;
            bf16x8 bfr[4];
#pragma unroll
            for (int ni = 0; ni < 4; ++ni) {
                int qr = rg * 64 + 16 * ni + li;
                bfr[ni] = *(const bf16x8*)((const char*)qs +
                           qr * 128 + (kbyte ^ ((qr & 7) << 4)));
            }
#pragma unroll
            for (int mi = 0; mi < 2; ++mi)
#pragma unroll
                for (int ni = 0; ni < 4; ++ni)
                    sacc[mi][ni] = __builtin_amdgcn_mfma_f32_16x16x32_bf16(
                        pjf[ks][mi], bfr[ni], sacc[mi][ni], 0, 0, 0);
        }

        // phase B: P=(exp+eps)/16 -> Pl[rg]
#pragma unroll
        for (int mi = 0; mi < 2; ++mi) {
            int m0 = 32 * wq + 16 * mi + 4 * g;
#pragma unroll
            for (int ni = 0; ni < 4; ++ni) {
                int row = 16 * ni + li;
                float e0 = (__expf(sacc[mi][ni][0]) + EPSF) * INV_SQRT_M;
                float e1 = (__expf(sacc[mi][ni][1]) + EPSF) * INV_SQRT_M;
                float e2 = (__expf(sacc[mi][ni][2]) + EPSF) * INV_SQRT_M;
                float e3 = (__expf(sacc[mi][ni][3]) + EPSF) * INV_SQRT_M;
                uint32_t u0 = (uint32_t)(uint16_t)f2bf(e0) |
                              ((uint32_t)(uint16_t)f2bf(e1) << 16);
                uint32_t u1 = (uint32_t)(uint16_t)f2bf(e2) |
                              ((uint32_t)(uint16_t)f2bf(e3) << 16);
                int byte = row * 256 + ((m0 * 2) ^ ((row & 7) << 4));
                *(uint2*)((char*)Pl[rg] + byte) = make_uint2(u0, u1);
            }
        }
        __syncthreads();               // P visible

        // phase C: out[rg][16wq..+15][0..79] += P @ kvT (col 64 = den)
        int rowA = 16 * wq + li;
        int abase = rowA * 256;
        int asw = (rowA & 7) << 4;
#pragma unroll
        for (int ks = 0; ks < 4; ++ks) {
            int kbyte = ks * 64 + g * 16;
            bf16x8 pa = *(const bf16x8*)((const char*)Pl[rg] + abase + (kbyte ^ asw));
#pragma unroll
            for (int ni = 0; ni < 5; ++ni) {
                int rowB = 16 * ni + li;
                bf16x8 bv = *(const bf16x8*)((const char*)kvl +
                             rowB * 256 + (kbyte ^ ((rowB & 7) << 4)));
                acc5[ni] = __builtin_amdgcn_mfma_f32_16x16x32_bf16(
                    pa, bv, acc5[ni], 0, 0, 0);
            }
        }
        __syncthreads();               // C reads done (Pl/kvl reusable)
    }

    // epilogue: den broadcast, divide, store
    float dj[4];
#pragma unroll
    for (int jj = 0; jj < 4; ++jj)
        dj[jj] = __shfl(acc5[4][jj], lane & 48) + EPSF;
#pragma unroll
    for (int ni = 0; ni < 4; ++ni) {
        int d = 16 * ni + li;
#pragma unroll
        for (int jj = 0; jj < 4; ++jj) {
            int n = rb * 128 + rg * 64 + 16 * wq + 4 * g + jj;
            attn[((size_t)b * 4096 + n) * 1024 + h * 64 + d] =
                f2bf(acc5[ni][jj] / dj[jj]);
        }
    }
}

extern "C" void kernel_launch(void* const* d_in, const int* in_sizes, int n_in,
                              void* d_out, int out_size, void* d_ws, size_t ws_size,
                              hipStream_t stream) {
    const float* x      = (const float*)d_in[0];
    const float* w_qkv  = (const float*)d_in[1];
    const float* b_qkv  = (const float*)d_in[2];
    const float* w_out  = (const float*)d_in[3];
    const float* b_out  = (const float*)d_in[4];
    const float* proj   = (const float*)d_in[5];
    float* out = (float*)d_out;

    // workspace layout (bytes), total ~139.5 MiB
    char* w = (char*)d_ws;
    short* xb     = (short*)(w);                        // 32 MiB -> kvpart overlay
    short* wqT    = (short*)(w + 33554432);             // 6 MiB
    short* wOT    = (short*)(w + 39845888);             // 2 MiB
    short* Qh     = (short*)(w + 41943040);             // 32 MiB (swz, *DN)
    short* Kh     = (short*)(w + 75497472);             // 32 MiB (swz, *DN) -> attn
    short* Vt     = (short*)(w + 109051904);            // 32 MiB transposed n-swz
    float* kvpart = (float*)(w);                        // overlay (xb dead)
    float* kspart = (float*)(w + 142606336);            // 512 KiB
    short* kvsT   = (short*)(w + 143130624);            // 2.5 MiB [64][80][256]
    short* pjb    = (short*)(w + 145752064);            // 512 KiB
    short* attn   = Kh;                                 // overlay (Kh dead)

    prep<<<dim3(18432), 256, 0, stream>>>(x, xb, w_qkv, wqT, w_out, wOT, proj, pjb);
    mfma_gemm_qkv<<<dim3(3072), 512, 0, stream>>>(xb, wqT, b_qkv, Qh, Kh, Vt);
    fmap_mfma<<<dim3(8, 64), 256, 0, stream>>>(Kh, Vt, pjb, kvpart, kspart);
    reduce_kv<<<dim3(5, 64), 256, 0, stream>>>(kvpart, kspart, kvsT);
    contract_mfma<<<dim3(32, 64), 512, 0, stream>>>(Qh, pjb, kvsT, attn);
    mfma_gemm_out<<<dim3(256), 512, 0, stream>>>(attn, wOT, b_out, out);
}

// Round 15
// 294.426 us; speedup vs baseline: 1.0303x; 1.0303x over previous
//
#include <hip/hip_runtime.h>
#include <hip/hip_bf16.h>
#include <stdint.h>

// ---------------------------------------------------------------------------
// Performer attention, round 14: best-of config (r12 qkv 8-wave, r11 contract
// 4-wave, r8 gemm_out, merged prep) + kvpart f32->bf16 (halves partial
// round-trip traffic; partials were re-rounded to bf16 at kvsT anyway).
// ---------------------------------------------------------------------------

#define DN 0.35355339059327379f   // 64^-0.25
#define EPSF 1e-6f
#define INV_SQRT_M 0.0625f        // 1/sqrt(256)

typedef __attribute__((ext_vector_type(8))) short bf16x8;
typedef __attribute__((ext_vector_type(4))) float f32x4;

static __device__ __forceinline__ short f2bf(float f) {
    __hip_bfloat16 h = __float2bfloat16(f);
    return *(short*)&h;
}
static __device__ __forceinline__ float bf2f(short s) {
    union { uint32_t i; float f; } c; c.i = ((uint32_t)(uint16_t)s) << 16; return c.f;
}
static __device__ __forceinline__ void gload16(const void* g, void* l) {
    __builtin_amdgcn_global_load_lds(
        (const __attribute__((address_space(1))) void*)g,
        (__attribute__((address_space(3))) void*)l,
        16, 0, 0);
}

// ---------------- K0: merged prep (x->bf16, w transposes, proj swizzle) ----
__global__ __launch_bounds__(256) void prep(const float* __restrict__ X,
                                            short* __restrict__ Xb,
                                            const float* __restrict__ Wq,
                                            short* __restrict__ WqT,
                                            const float* __restrict__ Wo,
                                            short* __restrict__ WoT,
                                            const float* __restrict__ proj,
                                            short* __restrict__ pjb) {
    __shared__ short tile[64][66];
    int b = blockIdx.x, t = threadIdx.x;
    if (b < 16384) {                           // conv_x
        int i = b * 256 + t;
        float4 v = ((const float4*)X)[i];
        short4 o;
        o.x = f2bf(v.x); o.y = f2bf(v.y); o.z = f2bf(v.z); o.w = f2bf(v.w);
        ((short4*)Xb)[i] = o;
    } else if (b < 17152) {                    // convt wq (48x16)
        int idx = b - 16384;
        int k0 = (idx / 48) * 64, n0 = (idx % 48) * 64;
        const int K = 1024, NN = 3072;
        for (int i = t; i < 4096; i += 256) {
            int r = i >> 6, c = i & 63;
            tile[r][c] = f2bf(Wq[(size_t)(k0 + r) * NN + n0 + c]);
        }
        __syncthreads();
        for (int i = t; i < 4096; i += 256) {
            int r = i >> 6, c = i & 63;
            WqT[(size_t)(n0 + r) * K + k0 + c] = tile[c][r];
        }
    } else if (b < 17408) {                    // convt wo (16x16)
        int idx = b - 17152;
        int k0 = (idx / 16) * 64, n0 = (idx % 16) * 64;
        const int K = 1024, NN = 1024;
        for (int i = t; i < 4096; i += 256) {
            int r = i >> 6, c = i & 63;
            tile[r][c] = f2bf(Wo[(size_t)(k0 + r) * NN + n0 + c]);
        }
        __syncthreads();
        for (int i = t; i < 4096; i += 256) {
            int r = i >> 6, c = i & 63;
            WoT[(size_t)(n0 + r) * K + k0 + c] = tile[c][r];
        }
    } else {                                   // conv_proj
        int e = (b - 17408) * 256 + t;
        int m = (e >> 6) & 255, d = e & 63;
        int base = e & ~63;
        pjb[base + (d ^ ((m & 7) << 3))] = f2bf(proj[e]);
    }
}

// ---------------- K1: 8-wave MFMA GEMM -> Q,K (swz,*DN), V^T ---------------
__global__ __launch_bounds__(512, 4) void mfma_gemm_qkv(
        const short* __restrict__ A, const short* __restrict__ BT,
        const float* __restrict__ bias,
        short* __restrict__ Qh, short* __restrict__ Kh, short* __restrict__ Vt) {
    __shared__ __align__(16) char smem[65536];
    const int K = 1024;
    int t = threadIdx.x, lane = t & 63, w = t >> 6;
    int li = lane & 15, g = lane >> 4;
    int wm = w >> 2, wn = w & 3;
    int lin = blockIdx.x;                        // 3072 = 24 x 128, plain
    int bx = lin % 24, by = lin / 24;
    int rowBase = by * 128, colBase = bx * 128;

    const char* aSrc[2]; const char* bSrc[2]; int aOff[2];
#pragma unroll
    for (int c = 0; c < 2; ++c) {
        int idx = c * 512 + t;
        int r = idx >> 3, s = t & 7;
        aOff[c] = idx * 16;
        aSrc[c] = (const char*)(A + (size_t)(rowBase + r) * K + ((s ^ (r & 7)) * 8));
        bSrc[c] = (const char*)(BT + (size_t)(colBase + r) * K + ((s ^ (r & 7)) * 8));
    }

    f32x4 acc[4][2];
#pragma unroll
    for (int m = 0; m < 4; ++m)
#pragma unroll
        for (int n = 0; n < 2; ++n) acc[m][n] = (f32x4){0.f, 0.f, 0.f, 0.f};

#pragma unroll
    for (int c = 0; c < 2; ++c) {
        gload16(aSrc[c], smem + aOff[c]);
        gload16(bSrc[c], smem + 16384 + aOff[c]);
    }

    int swz = (li & 7) << 4;

    for (int tt = 0; tt < 16; ++tt) {
        int cur = tt & 1;
        if (tt < 15) {
            char* d = smem + (cur ^ 1) * 32768;
#pragma unroll
            for (int c = 0; c < 2; ++c) {
                gload16(aSrc[c] + (size_t)(tt + 1) * 128, d + aOff[c]);
                gload16(bSrc[c] + (size_t)(tt + 1) * 128, d + 16384 + aOff[c]);
            }
            asm volatile("s_waitcnt vmcnt(4)" ::: "memory");
        } else {
            asm volatile("s_waitcnt vmcnt(0)" ::: "memory");
        }
        __builtin_amdgcn_sched_barrier(0);
        __builtin_amdgcn_s_barrier();
        __builtin_amdgcn_sched_barrier(0);
        __builtin_amdgcn_s_setprio(1);
        const char* bA = smem + cur * 32768;
        const char* bB = bA + 16384;
#pragma unroll
        for (int ks = 0; ks < 2; ++ks) {
            int kb = ks * 64 + g * 16;
            bf16x8 af[4], bv[2];
#pragma unroll
            for (int m = 0; m < 4; ++m)
                af[m] = *(const bf16x8*)(bA + (wm * 64 + m * 16 + li) * 128 + (kb ^ swz));
#pragma unroll
            for (int n = 0; n < 2; ++n)
                bv[n] = *(const bf16x8*)(bB + (wn * 32 + n * 16 + li) * 128 + (kb ^ swz));
#pragma unroll
            for (int m = 0; m < 4; ++m)
#pragma unroll
                for (int n = 0; n < 2; ++n)
                    acc[m][n] = __builtin_amdgcn_mfma_f32_16x16x32_bf16(
                        af[m], bv[n], acc[m][n], 0, 0, 0);
        }
        __builtin_amdgcn_s_setprio(0);
        __builtin_amdgcn_sched_barrier(0);
        __builtin_amdgcn_s_barrier();
        __builtin_amdgcn_sched_barrier(0);
    }

    float bcol[2];
#pragma unroll
    for (int n = 0; n < 2; ++n) bcol[n] = bias[colBase + wn * 32 + n * 16 + li];
    int whichB = colBase >> 10;

    if (whichB == 2) {
#pragma unroll
        for (int n = 0; n < 2; ++n) {
            int gc = colBase + wn * 32 + n * 16 + li;
            int hh = (gc & 1023) >> 6, dd = gc & 63;
#pragma unroll
            for (int m = 0; m < 4; ++m) {
                int gr0 = rowBase + wm * 64 + m * 16 + g * 4;
                int b = gr0 >> 12, nn0 = gr0 & 4095;
                short4 o;
                o.x = f2bf(acc[m][n][0] + bcol[n]);
                o.y = f2bf(acc[m][n][1] + bcol[n]);
                o.z = f2bf(acc[m][n][2] + bcol[n]);
                o.w = f2bf(acc[m][n][3] + bcol[n]);
                int nsw = (nn0 & ~63) | ((nn0 & 63) ^ ((dd & 7) << 3));
                *(short4*)&Vt[((size_t)(b * 16 + hh) * 64 + dd) * 4096 + nsw] = o;
            }
        }
    } else {
        short* dst = (whichB == 0) ? Qh : Kh;
        int hh = ((colBase + wn * 32) & 1023) >> 6;
        float* wreg = (float*)(smem + w * 4608);   // [32][36] f32
#pragma unroll
        for (int r = 0; r < 2; ++r) {
#pragma unroll
            for (int fr2 = 0; fr2 < 2; ++fr2)
#pragma unroll
                for (int n = 0; n < 2; ++n)
#pragma unroll
                    for (int jj = 0; jj < 4; ++jj)
                        wreg[(fr2 * 16 + g * 4 + jj) * 36 + n * 16 + li] =
                            (acc[2 * r + fr2][n][jj] + bcol[n]) * DN;
            int row2 = lane >> 1, h2 = lane & 1;
            int tok = rowBase + wm * 64 + r * 32 + row2;
            int b = tok >> 12, nn = tok & 4095;
            size_t base = ((size_t)(b * 16 + hh) * 4096 + nn) * 64;
#pragma unroll
            for (int k = 0; k < 2; ++k) {
                float4 v0 = *(const float4*)&wreg[row2 * 36 + h2 * 16 + k * 8];
                float4 v1 = *(const float4*)&wreg[row2 * 36 + h2 * 16 + k * 8 + 4];
                bf16x8 ov;
                ov[0] = f2bf(v0.x); ov[1] = f2bf(v0.y);
                ov[2] = f2bf(v0.z); ov[3] = f2bf(v0.w);
                ov[4] = f2bf(v1.x); ov[5] = f2bf(v1.y);
                ov[6] = f2bf(v1.z); ov[7] = f2bf(v1.w);
                int dgrp = ((wn & 1) * 4 + h2 * 2 + k) ^ (tok & 7);
                *(bf16x8*)&dst[base + dgrp * 8] = ov;
            }
            __builtin_amdgcn_s_barrier();
        }
    }
}

// ------- r8 256x256 8-phase GEMM core (used by gemm_out only) --------------
template<int Q, int S>
static __device__ __forceinline__ void phase_compute(
        const char* smem, int tt, int wm, int wn, int li, int g, int swz,
        f32x4 (&acc)[2][4][2][2]) {
    const char* bA = smem + ((tt & 1) << 16) + (Q << 14);
    const char* bB = smem + ((tt & 1) << 16) + 32768 + (S << 14);
    bf16x8 af[4][2], bf[2][2];
#pragma unroll
    for (int fr = 0; fr < 4; ++fr) {
        int row = wm * 64 + fr * 16 + li;
#pragma unroll
        for (int kk = 0; kk < 2; ++kk)
            af[fr][kk] = *(const bf16x8*)(bA + row * 128 + ((kk * 64 + g * 16) ^ swz));
    }
#pragma unroll
    for (int fn = 0; fn < 2; ++fn) {
        int row = wn * 32 + fn * 16 + li;
#pragma unroll
        for (int kk = 0; kk < 2; ++kk)
            bf[fn][kk] = *(const bf16x8*)(bB + row * 128 + ((kk * 64 + g * 16) ^ swz));
    }
    __builtin_amdgcn_s_setprio(1);
#pragma unroll
    for (int kk = 0; kk < 2; ++kk)
#pragma unroll
        for (int fr = 0; fr < 4; ++fr)
#pragma unroll
            for (int fn = 0; fn < 2; ++fn)
                acc[Q][fr][S][fn] = __builtin_amdgcn_mfma_f32_16x16x32_bf16(
                    af[fr][kk], bf[fn][kk], acc[Q][fr][S][fn], 0, 0, 0);
    __builtin_amdgcn_s_setprio(0);
}

static __device__ __forceinline__ void gemm_core256(const short* __restrict__ A,
                                                    const short* __restrict__ BT,
                                                    int rowBase, int colBase,
                                                    char* smem,
                                                    f32x4 (&acc)[2][4][2][2]) {
    const int K = 1024;
    int t = threadIdx.x, lane = t & 63;
    int li = lane & 15, g = lane >> 4;
    int w = t >> 6, wm = w >> 2, wn = w & 3;
    int swz = (li & 7) << 4;

    int idxA = t, idxB = 512 + t;
    int rA = idxA >> 3, sA = idxA & 7;
    int rB = idxB >> 3, sB = idxB & 7;
    const char* Ab = (const char*)(A + (size_t)rowBase * K);
    const char* Bb = (const char*)(BT + (size_t)colBase * K);
    int srcOffA = rA * 2048 + ((sA ^ (rA & 7)) * 16);
    int srcOffB = rB * 2048 + ((sB ^ (rB & 7)) * 16);
    int dstOffA = idxA * 16, dstOffB = idxB * 16;

#define STG(op_, half_, tile_) do {                                           \
    char* d_ = smem + (((tile_) & 1) << 16) + ((op_) << 15) + ((half_) << 14);\
    const char* s_ = ((op_) ? Bb : Ab) + (half_) * 262144 + (tile_) * 128;    \
    gload16(s_ + srcOffA, d_ + dstOffA);                                      \
    gload16(s_ + srcOffB, d_ + dstOffB);                                      \
} while (0)

#define PH(q_, s_, vm_, dost_, sop_, shalf_, stile_) do {                     \
    if (dost_) STG(sop_, shalf_, stile_);                                     \
    asm volatile("s_waitcnt vmcnt(" #vm_ ")" ::: "memory");                   \
    __builtin_amdgcn_sched_barrier(0);                                        \
    __builtin_amdgcn_s_barrier();                                             \
    __builtin_amdgcn_sched_barrier(0);                                        \
    phase_compute<q_, s_>(smem, tt, wm, wn, li, g, swz, acc);                 \
} while (0)

#pragma unroll
    for (int q = 0; q < 2; ++q)
#pragma unroll
        for (int fr = 0; fr < 4; ++fr)
#pragma unroll
            for (int s = 0; s < 2; ++s)
#pragma unroll
                for (int fn = 0; fn < 2; ++fn)
                    acc[q][fr][s][fn] = (f32x4){0.f, 0.f, 0.f, 0.f};

    STG(1, 0, 0);
    STG(0, 1, 0);
    STG(0, 0, 0);
    STG(1, 1, 0);
    STG(1, 0, 1);
    STG(0, 1, 1);

    for (int tt = 0; tt < 14; ++tt) {
        PH(0, 0,  8, true, 0, 0, tt + 1);
        PH(1, 0, 12, true, 1, 1, tt + 1);
        PH(1, 1, 10, true, 1, 0, tt + 2);
        PH(0, 1, 12, true, 0, 1, tt + 2);
    }
    {
        int tt = 14;
        PH(0, 0,  8, true, 0, 0, 15);
        PH(1, 0, 12, true, 1, 1, 15);
        PH(1, 1,  8, false, 0, 0, 0);
        PH(0, 1,  8, false, 0, 0, 0);
    }
    {
        int tt = 15;
        PH(0, 0, 2, false, 0, 0, 0);
        PH(1, 0, 4, false, 0, 0, 0);
        PH(1, 1, 0, false, 0, 0, 0);
        PH(0, 1, 0, false, 0, 0, 0);
    }
    __builtin_amdgcn_s_barrier();
#undef PH
#undef STG
}

// ---------------- K5: 8-phase MFMA GEMM -> d_out f32 -----------------------
__global__ __launch_bounds__(512) void mfma_gemm_out(
        const short* __restrict__ A, const short* __restrict__ BT,
        const float* __restrict__ bias, float* __restrict__ C) {
    __shared__ __align__(16) char smem[131072];
    int lin = blockIdx.x;                        // 256 = 4 x 64
    int bx = lin & 3, by = lin >> 2;
    int rowBase = by * 256, colBase = bx * 256;

    f32x4 acc[2][4][2][2];
    gemm_core256(A, BT, rowBase, colBase, smem, acc);

    int t = threadIdx.x, lane = t & 63, w = t >> 6;
    int li = lane & 15, g = lane >> 4, wm = w >> 2, wn = w & 3;
    float bcol[2][2];
#pragma unroll
    for (int s = 0; s < 2; ++s)
#pragma unroll
        for (int fn = 0; fn < 2; ++fn)
            bcol[s][fn] = bias[colBase + s * 128 + wn * 32 + fn * 16 + li];

    float* wreg = (float*)(smem + w * 5632);     // [32][44] f32 per wave (pad)
#pragma unroll
    for (int q = 0; q < 2; ++q)
#pragma unroll
        for (int fp = 0; fp < 2; ++fp)
#pragma unroll
            for (int s = 0; s < 2; ++s) {
#pragma unroll
                for (int fr2 = 0; fr2 < 2; ++fr2)
#pragma unroll
                    for (int fn = 0; fn < 2; ++fn)
#pragma unroll
                        for (int jj = 0; jj < 4; ++jj)
                            wreg[(fr2 * 16 + g * 4 + jj) * 44 + fn * 16 + li] =
                                acc[q][fp * 2 + fr2][s][fn][jj] + bcol[s][fn];
                int row2 = lane >> 1, hh2 = lane & 1;
                int gr = rowBase + q * 128 + wm * 64 + fp * 32 + row2;
                float* cp = C + (size_t)gr * 1024 + colBase + s * 128 + wn * 32 + hh2 * 16;
#pragma unroll
                for (int k = 0; k < 4; ++k)
                    *(float4*)&cp[k * 4] = *(const float4*)&wreg[row2 * 44 + hh2 * 16 + k * 4];
            }
}

// ------- K2: MFMA K feature map + kv/ksum partials (bf16 partials) ---------
__global__ __launch_bounds__(256) void fmap_mfma(const short* __restrict__ Kh,
                                                 const short* __restrict__ Vt,
                                                 const short* __restrict__ pjb,
                                                 short* __restrict__ kvpart,
                                                 float* __restrict__ kspart) {
    int bh = blockIdx.y, ch = blockIdx.x, h = bh & 15;
    int t = threadIdx.x, lane = t & 63, w = t >> 6;
    int g = lane >> 4, li = lane & 15;
    __shared__ __align__(16) short kt[64 * 64];     //  8KB [n][d] swz
    __shared__ __align__(16) short vt[64 * 64];     //  8KB [d][n] swz
    __shared__ __align__(16) short Pl[4][64 * 40];  // 20KB per-wave, 80B rows
    __shared__ __align__(16) float maxw[4][64];     //  1KB

    const short* kbase = Kh + ((size_t)bh * 4096 + ch * 512) * 64;
    const short* vbase = Vt + (size_t)bh * 64 * 4096 + ch * 512;
    int swz = (li & 7) << 4;

    bf16x8 pjf[2][4];
    {
        const char* ph = (const char*)(pjb + (size_t)h * 16384);
#pragma unroll
        for (int ks = 0; ks < 2; ++ks)
#pragma unroll
            for (int mi = 0; mi < 4; ++mi)
                pjf[ks][mi] = *(const bf16x8*)(ph +
                    (64 * w + 16 * mi + li) * 128 + ((ks * 64 + g * 16) ^ swz));
    }

    {
#pragma unroll
        for (int c2 = 0; c2 < 2; ++c2) {
            int c = 2 * w + c2;
            gload16(kbase + c * 512 + lane * 8, kt + c * 512);
            int d = 8 * c + (lane >> 3);
            gload16(vbase + (size_t)d * 4096 + (lane & 7) * 8, vt + c * 512);
        }
    }
    __syncthreads();

    f32x4 acc[4][4];
#pragma unroll
    for (int i = 0; i < 4; ++i)
#pragma unroll
        for (int j = 0; j < 4; ++j) acc[i][j] = (f32x4){0.f, 0.f, 0.f, 0.f};
    float ksacc[4] = {0.f, 0.f, 0.f, 0.f};

    for (int tile = 0; tile < 8; ++tile) {
        bf16x8 rk0, rk1, rv0, rv1;
        if (tile < 7) {
            int c0 = 2 * w, c1 = 2 * w + 1;
            size_t kof = (size_t)((tile + 1) * 64) * 64;
            rk0 = *(const bf16x8*)(kbase + kof + c0 * 512 + lane * 8);
            rk1 = *(const bf16x8*)(kbase + kof + c1 * 512 + lane * 8);
            int d0 = 8 * c0 + (lane >> 3), d1 = 8 * c1 + (lane >> 3);
            rv0 = *(const bf16x8*)(vbase + (size_t)d0 * 4096 + (tile + 1) * 64 + (lane & 7) * 8);
            rv1 = *(const bf16x8*)(vbase + (size_t)d1 * 4096 + (tile + 1) * 64 + (lane & 7) * 8);
        }

        f32x4 sacc[4][4];
#pragma unroll
        for (int i = 0; i < 4; ++i)
#pragma unroll
            for (int j = 0; j < 4; ++j) sacc[i][j] = (f32x4){0.f, 0.f, 0.f, 0.f};
#pragma unroll
        for (int ks = 0; ks < 2; ++ks) {
            int kb = ks * 64 + g * 16;
            bf16x8 afr[4];
#pragma unroll
            for (int ni = 0; ni < 4; ++ni)
                afr[ni] = *(const bf16x8*)((const char*)kt +
                           (16 * ni + li) * 128 + (kb ^ swz));
#pragma unroll
            for (int ni = 0; ni < 4; ++ni)
#pragma unroll
                for (int mi = 0; mi < 4; ++mi)
                    sacc[ni][mi] = __builtin_amdgcn_mfma_f32_16x16x32_bf16(
                        afr[ni], pjf[ks][mi], sacc[ni][mi], 0, 0, 0);
        }

        float mxl[4][4];
#pragma unroll
        for (int ni = 0; ni < 4; ++ni)
#pragma unroll
            for (int jj = 0; jj < 4; ++jj) {
                float m0 = fmaxf(sacc[ni][0][jj], sacc[ni][1][jj]);
                float m1 = fmaxf(sacc[ni][2][jj], sacc[ni][3][jj]);
                mxl[ni][jj] = fmaxf(m0, m1);
            }
#pragma unroll
        for (int off = 1; off <= 8; off <<= 1)
#pragma unroll
            for (int ni = 0; ni < 4; ++ni)
#pragma unroll
                for (int jj = 0; jj < 4; ++jj)
                    mxl[ni][jj] = fmaxf(mxl[ni][jj], __shfl_xor(mxl[ni][jj], off));
        if (li == 0) {
#pragma unroll
            for (int ni = 0; ni < 4; ++ni)
                *(float4*)&maxw[w][16 * ni + 4 * g] =
                    make_float4(mxl[ni][0], mxl[ni][1], mxl[ni][2], mxl[ni][3]);
        }
        __syncthreads();

#pragma unroll
        for (int hf = 0; hf < 2; ++hf) {
#pragma unroll
            for (int ni2 = 0; ni2 < 2; ++ni2) {
                int ni = 2 * hf + ni2;
                float4 a0 = *(const float4*)&maxw[0][16 * ni + 4 * g];
                float4 a1 = *(const float4*)&maxw[1][16 * ni + 4 * g];
                float4 a2 = *(const float4*)&maxw[2][16 * ni + 4 * g];
                float4 a3 = *(const float4*)&maxw[3][16 * ni + 4 * g];
                float mm[4];
                mm[0] = fmaxf(fmaxf(a0.x, a1.x), fmaxf(a2.x, a3.x));
                mm[1] = fmaxf(fmaxf(a0.y, a1.y), fmaxf(a2.y, a3.y));
                mm[2] = fmaxf(fmaxf(a0.z, a1.z), fmaxf(a2.z, a3.z));
                mm[3] = fmaxf(fmaxf(a0.w, a1.w), fmaxf(a2.w, a3.w));
#pragma unroll
                for (int mi = 0; mi < 4; ++mi) {
                    float p0 = (__expf(sacc[ni][mi][0] - mm[0]) + EPSF) * INV_SQRT_M;
                    float p1 = (__expf(sacc[ni][mi][1] - mm[1]) + EPSF) * INV_SQRT_M;
                    float p2 = (__expf(sacc[ni][mi][2] - mm[2]) + EPSF) * INV_SQRT_M;
                    float p3 = (__expf(sacc[ni][mi][3] - mm[3]) + EPSF) * INV_SQRT_M;
                    ksacc[mi] += (p0 + p1) + (p2 + p3);
                    uint32_t u0 = (uint32_t)(uint16_t)f2bf(p0) |
                                  ((uint32_t)(uint16_t)f2bf(p1) << 16);
                    uint32_t u1 = (uint32_t)(uint16_t)f2bf(p2) |
                                  ((uint32_t)(uint16_t)f2bf(p3) << 16);
                    int m_l = 16 * mi + li;
                    *(uint2*)((char*)Pl[w] + m_l * 80 + 32 * ni2 + 8 * g) =
                        make_uint2(u0, u1);
                }
            }
#pragma unroll
            for (int mi = 0; mi < 4; ++mi) {
                bf16x8 pa = *(const bf16x8*)((const char*)Pl[w] +
                             (16 * mi + li) * 80 + 16 * g);
#pragma unroll
                for (int di = 0; di < 4; ++di) {
                    bf16x8 bv = *(const bf16x8*)((const char*)vt +
                                 (16 * di + li) * 128 + ((64 * hf + 16 * g) ^ swz));
                    acc[mi][di] = __builtin_amdgcn_mfma_f32_16x16x32_bf16(
                        pa, bv, acc[mi][di], 0, 0, 0);
                }
            }
        }
        __syncthreads();
        if (tile < 7) {
            int c0 = 2 * w, c1 = 2 * w + 1;
            *(bf16x8*)((char*)kt + c0 * 1024 + lane * 16) = rk0;
            *(bf16x8*)((char*)kt + c1 * 1024 + lane * 16) = rk1;
            *(bf16x8*)((char*)vt + c0 * 1024 + lane * 16) = rv0;
            *(bf16x8*)((char*)vt + c1 * 1024 + lane * 16) = rv1;
            __syncthreads();
        }
    }

#pragma unroll
    for (int mi = 0; mi < 4; ++mi) {
        ksacc[mi] += __shfl_xor(ksacc[mi], 16);
        ksacc[mi] += __shfl_xor(ksacc[mi], 32);
    }
    if (lane < 16) {
#pragma unroll
        for (int mi = 0; mi < 4; ++mi)
            kspart[(bh * 8 + ch) * 256 + 64 * w + 16 * mi + li] = ksacc[mi];
    }
    // kv partials -> bf16 [d][m] (halves round-trip traffic)
    short* kvb = kvpart + (size_t)(bh * 8 + ch) * 16384;
#pragma unroll
    for (int mi = 0; mi < 4; ++mi)
#pragma unroll
        for (int di = 0; di < 4; ++di) {
            int d = 16 * di + li, m0 = 64 * w + 16 * mi + 4 * g;
            short4 o;
            o.x = f2bf(acc[mi][di][0]); o.y = f2bf(acc[mi][di][1]);
            o.z = f2bf(acc[mi][di][2]); o.w = f2bf(acc[mi][di][3]);
            *(short4*)&kvb[d * 256 + m0] = o;
        }
}

// ------- K3: reduce bf16 partials -> kvT_sw bf16 [bh][80][256] -------------
__global__ __launch_bounds__(256) void reduce_kv(const short* __restrict__ kvpart,
                                                 const float* __restrict__ kspart,
                                                 short* __restrict__ kvsT) {
    int bh = blockIdx.y, bx = blockIdx.x, t = threadIdx.x;
    if (bx < 4) {
#pragma unroll
        for (int i = 0; i < 16; ++i) {
            int idx = t + i * 256;
            int d = 16 * bx + (idx >> 8), m = idx & 255;
            float s = 0.f;
            size_t base = ((size_t)(bh * 8) * 64 + d) * 256 + m;
#pragma unroll
            for (int c = 0; c < 8; ++c) s += bf2f(kvpart[base + (size_t)c * 16384]);
            int widx = (m & 128) + ((m & 127) ^ ((d & 7) << 3));
            kvsT[((size_t)bh * 80 + d) * 256 + widx] = f2bf(s);
        }
    } else {
        float s = 0.f;
#pragma unroll
        for (int c = 0; c < 8; ++c) s += kspart[((bh * 8 + c) << 8) + t];
        kvsT[((size_t)bh * 80 + 64) * 256 + t] = f2bf(s);
        for (int i = t; i < 15 * 256; i += 256) {
            int r = 65 + (i >> 8), cc = i & 255;
            kvsT[((size_t)bh * 80 + r) * 256 + cc] = 0;
        }
    }
}

// ------- K4: MFMA contract, QBLK=128, proj in regs, LDS 52KB (r11/r12) -----
__global__ __launch_bounds__(256) void contract_mfma(
        const short* __restrict__ Qh,      // pre-swizzled, *DN
        const short* __restrict__ pjb,     // pre-swizzled bf16
        const short* __restrict__ kvsT,    // pre-swizzled bf16 [bh][80][256]
        short* __restrict__ attn) {
    int bh = blockIdx.y, rb = blockIdx.x, h = bh & 15, b = bh >> 4;
    int t = threadIdx.x, lane = t & 63, w = t >> 6;
    __shared__ __align__(16) short qs[128 * 64];   // 16KB [row][d]  (swz)
    __shared__ __align__(16) short Pl[64 * 128];   // 16KB [row][m]  (swz)
    __shared__ __align__(16) short kvl[80 * 128];  // 20KB [d'][m]   (swz)

    {
        const short* src = Qh + ((size_t)bh * 4096 + rb * 128) * 64;
#pragma unroll
        for (int c2 = 0; c2 < 4; ++c2) {
            int c = 4 * w + c2;
            gload16(src + (c * 8 + (lane >> 3)) * 64 + (lane & 7) * 8,
                    qs + c * 512);
        }
    }

    f32x4 acc5[2][5];
#pragma unroll
    for (int rg = 0; rg < 2; ++rg)
#pragma unroll
        for (int i = 0; i < 5; ++i) acc5[rg][i] = (f32x4){0.f, 0.f, 0.f, 0.f};

    int g = lane >> 4, li = lane & 15;

    for (int half = 0; half < 2; ++half) {
        bf16x8 pjf[2][2];
        {
            const char* ph = (const char*)(pjb + (size_t)h * 16384 + half * 8192);
#pragma unroll
            for (int ks = 0; ks < 2; ++ks)
#pragma unroll
                for (int mi = 0; mi < 2; ++mi) {
                    int mr = 32 * w + 16 * mi + li;
                    pjf[ks][mi] = *(const bf16x8*)(ph +
                        mr * 128 + ((ks * 64 + g * 16) ^ ((mr & 7) << 4)));
                }
        }
        const short* ksrc = kvsT + (size_t)bh * 80 * 256 + half * 128;
#pragma unroll
        for (int c2 = 0; c2 < 5; ++c2) {
            int c = 5 * w + c2;
            gload16(ksrc + (c * 4 + (lane >> 4)) * 256 + (lane & 15) * 8,
                    kvl + c * 512);
        }
        __syncthreads();

#pragma unroll
        for (int rg = 0; rg < 2; ++rg) {
            f32x4 sacc[2][4];
#pragma unroll
            for (int mi = 0; mi < 2; ++mi)
#pragma unroll
                for (int ni = 0; ni < 4; ++ni) sacc[mi][ni] = (f32x4){0.f, 0.f, 0.f, 0.f};
#pragma unroll
            for (int ks = 0; ks < 2; ++ks) {
                int kbyte = ks * 64 + g * 16;
                bf16x8 bfr[4];
#pragma unroll
                for (int ni = 0; ni < 4; ++ni) {
                    int qr = rg * 64 + 16 * ni + li;
                    bfr[ni] = *(const bf16x8*)((const char*)qs +
                               qr * 128 + (kbyte ^ ((qr & 7) << 4)));
                }
#pragma unroll
                for (int mi = 0; mi < 2; ++mi)
#pragma unroll
                    for (int ni = 0; ni < 4; ++ni)
                        sacc[mi][ni] = __builtin_amdgcn_mfma_f32_16x16x32_bf16(
                            pjf[ks][mi], bfr[ni], sacc[mi][ni], 0, 0, 0);
            }

#pragma unroll
            for (int mi = 0; mi < 2; ++mi) {
                int m0 = 32 * w + 16 * mi + 4 * g;
#pragma unroll
                for (int ni = 0; ni < 4; ++ni) {
                    int row = 16 * ni + li;
                    float e0 = (__expf(sacc[mi][ni][0]) + EPSF) * INV_SQRT_M;
                    float e1 = (__expf(sacc[mi][ni][1]) + EPSF) * INV_SQRT_M;
                    float e2 = (__expf(sacc[mi][ni][2]) + EPSF) * INV_SQRT_M;
                    float e3 = (__expf(sacc[mi][ni][3]) + EPSF) * INV_SQRT_M;
                    uint32_t u0 = (uint32_t)(uint16_t)f2bf(e0) |
                                  ((uint32_t)(uint16_t)f2bf(e1) << 16);
                    uint32_t u1 = (uint32_t)(uint16_t)f2bf(e2) |
                                  ((uint32_t)(uint16_t)f2bf(e3) << 16);
                    int byte = row * 256 + ((m0 * 2) ^ ((row & 7) << 4));
                    *(uint2*)((char*)Pl + byte) = make_uint2(u0, u1);
                }
            }
            __syncthreads();

            int rowA = 16 * w + li;
            int abase = rowA * 256;
            int asw = (rowA & 7) << 4;
#pragma unroll
            for (int ks = 0; ks < 4; ++ks) {
                int kbyte = ks * 64 + g * 16;
                bf16x8 pa = *(const bf16x8*)((const char*)Pl + abase + (kbyte ^ asw));
#pragma unroll
                for (int ni = 0; ni < 5; ++ni) {
                    int rowB = 16 * ni + li;
                    bf16x8 bv = *(const bf16x8*)((const char*)kvl +
                                 rowB * 256 + (kbyte ^ ((rowB & 7) << 4)));
                    acc5[rg][ni] = __builtin_amdgcn_mfma_f32_16x16x32_bf16(
                        pa, bv, acc5[rg][ni], 0, 0, 0);
                }
            }
            __syncthreads();
        }
    }

#pragma unroll
    for (int rg = 0; rg < 2; ++rg) {
        float dj[4];
#pragma unroll
        for (int jj = 0; jj < 4; ++jj)
            dj[jj] = __shfl(acc5[rg][4][jj], lane & 48) + EPSF;
#pragma unroll
        for (int ni = 0; ni < 4; ++ni) {
            int d = 16 * ni + li;
#pragma unroll
            for (int jj = 0; jj < 4; ++jj) {
                int n = rb * 128 + rg * 64 + 16 * w + 4 * g + jj;
                attn[((size_t)b * 4096 + n) * 1024 + h * 64 + d] =
                    f2bf(acc5[rg][ni][jj] / dj[jj]);
            }
        }
    }
}

extern "C" void kernel_launch(void* const* d_in, const int* in_sizes, int n_in,
                              void* d_out, int out_size, void* d_ws, size_t ws_size,
                              hipStream_t stream) {
    const float* x      = (const float*)d_in[0];
    const float* w_qkv  = (const float*)d_in[1];
    const float* b_qkv  = (const float*)d_in[2];
    const float* w_out  = (const float*)d_in[3];
    const float* b_out  = (const float*)d_in[4];
    const float* proj   = (const float*)d_in[5];
    float* out = (float*)d_out;

    // workspace layout (bytes), total ~139.5 MiB
    char* w = (char*)d_ws;
    short* xb     = (short*)(w);                        // 32 MiB -> kvpart overlay
    short* wqT    = (short*)(w + 33554432);             // 6 MiB
    short* wOT    = (short*)(w + 39845888);             // 2 MiB
    short* Qh     = (short*)(w + 41943040);             // 32 MiB (swz, *DN)
    short* Kh     = (short*)(w + 75497472);             // 32 MiB (swz, *DN) -> attn
    short* Vt     = (short*)(w + 109051904);            // 32 MiB transposed n-swz
    short* kvpart = (short*)(w);                        // 16 MiB overlay (xb dead)
    float* kspart = (float*)(w + 142606336);            // 512 KiB
    short* kvsT   = (short*)(w + 143130624);            // 2.5 MiB [64][80][256]
    short* pjb    = (short*)(w + 145752064);            // 512 KiB
    short* attn   = Kh;                                 // overlay (Kh dead)

    prep<<<dim3(18432), 256, 0, stream>>>(x, xb, w_qkv, wqT, w_out, wOT, proj, pjb);
    mfma_gemm_qkv<<<dim3(3072), 512, 0, stream>>>(xb, wqT, b_qkv, Qh, Kh, Vt);
    fmap_mfma<<<dim3(8, 64), 256, 0, stream>>>(Kh, Vt, pjb, kvpart, kspart);
    reduce_kv<<<dim3(5, 64), 256, 0, stream>>>(kvpart, kspart, kvsT);
    contract_mfma<<<dim3(32, 64), 256, 0, stream>>>(Qh, pjb, kvsT, attn);
    mfma_gemm_out<<<dim3(256), 512, 0, stream>>>(attn, wOT, b_out, out);
}